// Round 14
// baseline (184.664 us; speedup 1.0000x reference)
//
#include <hip/hip_runtime.h>
#include <math.h>

typedef _Float16 f16;
typedef __attribute__((ext_vector_type(8))) _Float16 f16x8;
typedef __attribute__((ext_vector_type(4))) _Float16 f16x4;
typedef __attribute__((ext_vector_type(4))) float f32x4;

constexpr int BATCH = 32;
constexpr int QL = 1024;
constexpr int KL = 1024;
constexpr int D = 128;
constexpr int BQ = 128;   // query rows per block (32 per wave, 2 halves)
constexpr int BK = 64;    // key rows per tile
constexpr int CT = 8;     // tiles per K-chunk (split-K x2)
constexpr int DKP = 136;  // sK row pitch in halves (272 B; bank-spread)
constexpr int BKP = 72;   // sVT row pitch in halves (144 B; bank-spread)

// scale * log2(e): softmax in exp2 domain; folded into Q fragments at load.
#define CSC 0.12752863187087177f

static __device__ __forceinline__ f16x4 pk4(float x, float y, float z, float w) {
  auto a = __builtin_amdgcn_cvt_pkrtz(x, y);
  auto b = __builtin_amdgcn_cvt_pkrtz(z, w);
  f16x4 h;
  h[0] = (f16)a[0]; h[1] = (f16)a[1]; h[2] = (f16)b[0]; h[3] = (f16)b[1];
  return h;
}
static __device__ __forceinline__ f16x8 pk8(float4 u, float4 v) {
  f16x4 a = pk4(u.x, u.y, u.z, u.w);
  f16x4 b = pk4(v.x, v.y, v.z, v.w);
  f16x8 h;
  h[0] = a[0]; h[1] = a[1]; h[2] = a[2]; h[3] = a[3];
  h[4] = b[0]; h[5] = b[1]; h[6] = b[2]; h[7] = b[3];
  return h;
}
static __device__ __forceinline__ f16x8 pk8v(f32x4 a, f32x4 b) {
  auto x0 = __builtin_amdgcn_cvt_pkrtz(a[0], a[1]);
  auto x1 = __builtin_amdgcn_cvt_pkrtz(a[2], a[3]);
  auto x2 = __builtin_amdgcn_cvt_pkrtz(b[0], b[1]);
  auto x3 = __builtin_amdgcn_cvt_pkrtz(b[2], b[3]);
  f16x8 h;
  h[0] = x0[0]; h[1] = x0[1]; h[2] = x1[0]; h[3] = x1[1];
  h[4] = x2[0]; h[5] = x2[1]; h[6] = x3[0]; h[7] = x3[1];
  return h;
}
static __device__ __forceinline__ f16x8 pk8s(float4 u, float4 v) {
  float4 a = {u.x * CSC, u.y * CSC, u.z * CSC, u.w * CSC};
  float4 b = {v.x * CSC, v.y * CSC, v.z * CSC, v.w * CSC};
  return pk8(a, b);
}

// ---- staging-row permutation for sK (VERIFIED numerically R4-R13).
// Swapped QK^T (A = K): sv[ct][r] at lane(quad) is key
//   (ct>>1)*32 + quad*8 + (ct&1)*4 + r  — exactly the PV B-operand layout.
static __device__ __forceinline__ int krp(int kk) {
  return ((kk >> 5) << 5) | (((kk >> 2) & 1) << 4) | (((kk >> 3) & 3) << 2) | (kk & 3);
}

// ---- issue global loads for tile T into reg set (KR,VR) — 256 threads
#define ISSUE(KR, VR, T)                                                   \
  do {                                                                     \
    const float4* Kt = (const float4*)(Kb + (size_t)(T) * BK * D);         \
    _Pragma("unroll")                                                      \
    for (int i_ = 0; i_ < 4; ++i_) {                                       \
      int cc_ = tid + i_ * 256;                                            \
      int row_ = cc_ >> 4, d04_ = (cc_ & 15) * 2;                          \
      KR[2 * i_]     = Kt[row_ * 32 + d04_];                               \
      KR[2 * i_ + 1] = Kt[row_ * 32 + d04_ + 1];                           \
    }                                                                      \
    const float* Vt = Vb + (size_t)(T) * BK * D;                           \
    _Pragma("unroll")                                                      \
    for (int i_ = 0; i_ < 2; ++i_) {                                       \
      int f_ = tid + i_ * 256;                                             \
      const float* base_ = Vt + (size_t)((f_ & 15) * 4) * D + (f_ >> 4) * 4; \
      VR[i_ * 4 + 0] = *(const float4*)(base_);                            \
      VR[i_ * 4 + 1] = *(const float4*)(base_ + D);                        \
      VR[i_ * 4 + 2] = *(const float4*)(base_ + 2 * D);                    \
      VR[i_ * 4 + 3] = *(const float4*)(base_ + 3 * D);                    \
    }                                                                      \
  } while (0)

// ---- convert+store reg set into LDS buffer NB (double-buffered)
#define DRAIN(KR, VR, NB)                                                  \
  do {                                                                     \
    _Pragma("unroll")                                                      \
    for (int i_ = 0; i_ < 4; ++i_) {                                       \
      int cc_ = tid + i_ * 256;                                            \
      int row_ = cc_ >> 4, d0_ = (cc_ & 15) * 8;                           \
      *(f16x8*)&sK[NB][krp(row_)][d0_] = pk8(KR[2 * i_], KR[2 * i_ + 1]);  \
    }                                                                      \
    _Pragma("unroll")                                                      \
    for (int i_ = 0; i_ < 2; ++i_) {                                       \
      int f_ = tid + i_ * 256;                                             \
      int k0_ = (f_ & 15) * 4, d0_ = (f_ >> 4) * 4;                        \
      float4 r0_ = VR[i_*4+0], r1_ = VR[i_*4+1], r2_ = VR[i_*4+2], r3_ = VR[i_*4+3]; \
      *(f16x4*)&sVT[NB][d0_ + 0][k0_] = pk4(r0_.x, r1_.x, r2_.x, r3_.x);   \
      *(f16x4*)&sVT[NB][d0_ + 1][k0_] = pk4(r0_.y, r1_.y, r2_.y, r3_.y);   \
      *(f16x4*)&sVT[NB][d0_ + 2][k0_] = pk4(r0_.z, r1_.z, r2_.z, r3_.z);   \
      *(f16x4*)&sVT[NB][d0_ + 3][k0_] = pk4(r0_.w, r1_.w, r2_.w, r3_.w);   \
    }                                                                      \
  } while (0)

// raw barrier: lgkmcnt(0) for LDS visibility, NO forced vmcnt(0) drain
#define TILE_BARRIER()                                                     \
  do {                                                                     \
    asm volatile("s_waitcnt lgkmcnt(0)" ::: "memory");                     \
    __builtin_amdgcn_s_barrier();                                          \
    asm volatile("" ::: "memory");                                         \
  } while (0)

// R13 post-mortem: attn_fwd < 41 us (below fill-kernel cutoff) — BQ=128 +
// split-K x2 beat the 7k/unit wall. Remaining controllable cost = attn +
// trailing combine dispatch (~8-10 us). This round: last-finisher split-K
// fixup INSIDE attn_fwd (threadfence + per-pair atomic counter; second
// finisher merges from its own registers + the other's partial, writes
// final O). Combine kernel gone; merges overlap still-running chunks.
__global__ __launch_bounds__(256, 2)
void attn_fwd(const float* __restrict__ Qp, const float* __restrict__ Kp,
              const float* __restrict__ Vp, const int* __restrict__ VLp,
              float* __restrict__ Op, float* __restrict__ wsO,
              float* __restrict__ wsL, int* __restrict__ wsC, int nks) {
  __shared__ f16 sK[2][BK][DKP];   // ROW-PERMUTED per krp() for swapped QK^T
  __shared__ f16 sVT[2][D][BKP];   // V tile transposed [d][kk]
  __shared__ int sN[32];           // batch -> ntiles
  __shared__ int sI[32];           // cost-rank -> batch
  __shared__ int sFlag;            // last-finisher flag

  const int tid  = threadIdx.x;
  const int wave = tid >> 6, lane = tid & 63;
  const int l16  = lane & 15, quad = lane >> 4;

  // ---- batch cost ranking (VERIFIED R1/R3: XCD binding -> FETCH 81->17 MB)
  if (tid < 32) sN[tid] = (VLp[tid] + BK - 1) / BK;
  __syncthreads();
  if (tid < 32) {
    int nb = sN[tid], r = 0;
    #pragma unroll
    for (int k = 0; k < 32; ++k) {
      int nk = sN[k];
      r += (nk > nb) || (nk == nb && k < tid);
    }
    sI[r] = tid;  // rank -> batch
  }
  __syncthreads();

  const int xcd = blockIdx.x & 7;
  const int i   = (int)blockIdx.x >> 3;  // local seq within XCD

  int b, qt, ks, lb, t0, t1, nt, vl;
  if (nks == 2) {
    // 64 items/XCD (4 lb x 8 qt x 2 ks), grid 512 = 2 blocks/CU.
    // CU pair (id, id+256): ks0(lb,qt) + ks1(3-lb,qt). Heavy-class ks0
    // pairs with light-class ks1 (usually empty -> instant exit).
    if (i < 32) { ks = 0; lb = i >> 3;              qt = i & 7; }
    else        { ks = 1; lb = 3 - ((i - 32) >> 3); qt = (i - 32) & 7; }
    const int gr = (lb == 0) ? xcd : (lb == 1) ? (15 - xcd)
                 : (lb == 2) ? (16 + xcd) : (31 - xcd);
    b  = sI[gr];
    vl = VLp[b];
    nt = (vl + BK - 1) / BK;
    t0 = ks * CT;
    t1 = min(nt, t0 + CT);
    if (t0 >= t1) return;  // empty chunk (uniform exit, after all barriers)
  } else {
    // fallback (small ws): full-chain schedule, grid 256, 1 block/CU
    ks = 0; lb = i >> 3; qt = i & 7;
    const int gr = (lb == 0) ? xcd : (lb == 1) ? (15 - xcd)
                 : (lb == 2) ? (16 + xcd) : (31 - xcd);
    b  = sI[gr];
    vl = VLp[b];
    nt = (vl + BK - 1) / BK;
    t0 = 0; t1 = nt;
  }

  const float* Kb = Kp + (size_t)b * KL * D;
  const float* Vb = Vp + (size_t)b * KL * D;

  // single staging reg set, distance-1 (two sets spill — R1)
  float4 kreg[8], vreg[8];

  // Q loads first (oldest in vmcnt order): 32 rows/wave, 2 halves of 16
  const float* Qb = Qp + ((size_t)(b * QL + qt * BQ + wave * 32 + l16)) * D;
  float4 qtmp[16];
  #pragma unroll
  for (int h = 0; h < 2; ++h)
    #pragma unroll
    for (int kc = 0; kc < 4; ++kc) {
      const float* p = Qb + h * 16 * D + kc * 32 + quad * 8;
      qtmp[h * 8 + 2 * kc]     = *(const float4*)p;
      qtmp[h * 8 + 2 * kc + 1] = *(const float4*)(p + 4);
    }

  ISSUE(kreg, vreg, t0);

  // Q as B-operand fragments (col=q, k=quad*8+j), CSC pre-folded
  f16x8 qf0[4], qf1[4];
  #pragma unroll
  for (int kc = 0; kc < 4; ++kc)
    qf0[kc] = pk8s(qtmp[2 * kc], qtmp[2 * kc + 1]);
  #pragma unroll
  for (int kc = 0; kc < 4; ++kc)
    qf1[kc] = pk8s(qtmp[8 + 2 * kc], qtmp[8 + 2 * kc + 1]);

  float ls0 = 0.f, ls1 = 0.f;
  f32x4 o0[8], o1[8];
  #pragma unroll
  for (int dt = 0; dt < 8; ++dt) {
    o0[dt] = (f32x4){0.f, 0.f, 0.f, 0.f};
    o1[dt] = (f32x4){0.f, 0.f, 0.f, 0.f};
  }

  // prologue: drain tile t0 into buffer 0
  DRAIN(kreg, vreg, 0);
  TILE_BARRIER();

  for (int t = t0; t < t1; ++t) {
    const int cur = (t - t0) & 1, nxt = cur ^ 1;
    const bool more = (t + 1 < t1);

    if (more) ISSUE(kreg, vreg, t + 1);

    // ---- S^T = K Q^T : each kf read feeds BOTH q-halves (2 MFMAs/read)
    f32x4 s0[4], s1[4];
    #pragma unroll
    for (int ct = 0; ct < 4; ++ct) {
      s0[ct] = (f32x4){0.f, 0.f, 0.f, 0.f};
      s1[ct] = (f32x4){0.f, 0.f, 0.f, 0.f};
      #pragma unroll
      for (int kc = 0; kc < 4; ++kc) {
        f16x8 kf = *(const f16x8*)&sK[cur][ct * 16 + l16][kc * 32 + quad * 8];
        s0[ct] = __builtin_amdgcn_mfma_f32_16x16x32_f16(kf, qf0[kc], s0[ct], 0, 0, 0);
        s1[ct] = __builtin_amdgcn_mfma_f32_16x16x32_f16(kf, qf1[kc], s1[ct], 0, 0, 0);
      }
    }

    // ---- key-padding mask, ONLY on the single partial tile (wave-uniform)
    if (t * BK + BK > vl) {
      #pragma unroll
      for (int ct = 0; ct < 4; ++ct) {
        int kb = t * BK + (ct >> 1) * 32 + (ct & 1) * 4 + quad * 8;
        #pragma unroll
        for (int r = 0; r < 4; ++r) {
          bool ok = (kb + r) < vl;
          s0[ct][r] = ok ? s0[ct][r] : -1.0e9f;
          s1[ct][r] = ok ? s1[ct][r] : -1.0e9f;
        }
      }
    }

    // ---- fixed-base softmax: p = 2^sv (VERIFIED R8-R13; base cancels in
    // o/l; split-K combining exactly associative)
    #pragma unroll
    for (int ct = 0; ct < 4; ++ct) {
      #pragma unroll
      for (int r = 0; r < 4; ++r) {
        float p0 = __builtin_amdgcn_exp2f(s0[ct][r]);
        float p1 = __builtin_amdgcn_exp2f(s1[ct][r]);
        s0[ct][r] = p0; ls0 += p0;
        s1[ct][r] = p1; ls1 += p1;
      }
    }
    f16x8 pa0 = pk8v(s0[0], s0[1]), pb0 = pk8v(s0[2], s0[3]);
    f16x8 pa1 = pk8v(s1[0], s1[1]), pb1 = pk8v(s1[2], s1[3]);

    // ---- O^T += V^T P^T : each vf read feeds BOTH q-halves
    #pragma unroll
    for (int dt = 0; dt < 8; ++dt) {
      f16x8 vf0 = *(const f16x8*)&sVT[cur][dt * 16 + l16][quad * 8];
      o0[dt] = __builtin_amdgcn_mfma_f32_16x16x32_f16(vf0, pa0, o0[dt], 0, 0, 0);
      o1[dt] = __builtin_amdgcn_mfma_f32_16x16x32_f16(vf0, pa1, o1[dt], 0, 0, 0);
      f16x8 vf1 = *(const f16x8*)&sVT[cur][dt * 16 + l16][32 + quad * 8];
      o0[dt] = __builtin_amdgcn_mfma_f32_16x16x32_f16(vf1, pb0, o0[dt], 0, 0, 0);
      o1[dt] = __builtin_amdgcn_mfma_f32_16x16x32_f16(vf1, pb1, o1[dt], 0, 0, 0);
    }

    // no barrier after the LAST tile (no further LDS writes — safe)
    if (more) {
      DRAIN(kreg, vreg, nxt);
      TILE_BARRIER();
    }
  }

  // ---- row sums across quad groups
  ls0 += __shfl_xor(ls0, 16);
  ls0 += __shfl_xor(ls0, 32);
  ls1 += __shfl_xor(ls1, 16);
  ls1 += __shfl_xor(ls1, 32);

  // ---- epilogue. Lane holds O^T[d=dt*16+quad*4+r][q] (contiguous d).
  const int row0 = qt * BQ + wave * 32;
  if (nks == 1 || nt <= CT) {
    float* Ob = Op + ((size_t)(b * QL + row0)) * D;
    const float i0 = 1.0f / ls0, i1 = 1.0f / ls1;
    #pragma unroll
    for (int dt = 0; dt < 8; ++dt) {
      float4 w0 = {o0[dt][0] * i0, o0[dt][1] * i0, o0[dt][2] * i0, o0[dt][3] * i0};
      float4 w1 = {o1[dt][0] * i1, o1[dt][1] * i1, o1[dt][2] * i1, o1[dt][3] * i1};
      *(float4*)&Ob[(size_t)l16 * D + dt * 16 + quad * 4]        = w0;
      *(float4*)&Ob[(size_t)(16 + l16) * D + dt * 16 + quad * 4] = w1;
    }
  } else {
    // split pair: write raw partial (ks=0 -> O region as scratch, ks=1 -> ws),
    // then last-finisher merges (replaces the attn_combine kernel).
    const int pair = b * 8 + qt;   // 0..255
    float* dst = (ks == 0)
        ? Op + ((size_t)(b * QL + row0)) * D
        : wsO + (size_t)pair * BQ * D + (size_t)(wave * 32) * D;
    #pragma unroll
    for (int dt = 0; dt < 8; ++dt) {
      float4 w0 = {o0[dt][0], o0[dt][1], o0[dt][2], o0[dt][3]};
      float4 w1 = {o1[dt][0], o1[dt][1], o1[dt][2], o1[dt][3]};
      *(float4*)&dst[(size_t)l16 * D + dt * 16 + quad * 4]        = w0;
      *(float4*)&dst[(size_t)(16 + l16) * D + dt * 16 + quad * 4] = w1;
    }
    if (quad == 0) {
      wsL[(pair * 2 + ks) * 128 + wave * 32 + l16]      = ls0;
      wsL[(pair * 2 + ks) * 128 + wave * 32 + 16 + l16] = ls1;
    }

    // ---- release: make partial visible device-wide, then count arrival
    __threadfence();
    __syncthreads();
    if (tid == 0) sFlag = atomicAdd(&wsC[pair], 1);
    __syncthreads();
    if (sFlag == 1) {
      // I'm the second finisher: acquire, merge own regs + other's partial.
      __threadfence();
      const int oks = ks ^ 1;
      const float* osrc = (oks == 0)
          ? Op + ((size_t)(b * QL + row0)) * D
          : wsO + (size_t)pair * BQ * D + (size_t)(wave * 32) * D;
      const float ol0 = wsL[(pair * 2 + oks) * 128 + wave * 32 + l16];
      const float ol1 = wsL[(pair * 2 + oks) * 128 + wave * 32 + 16 + l16];
      const float i0 = 1.0f / (ls0 + ol0), i1 = 1.0f / (ls1 + ol1);
      float* Ob = Op + ((size_t)(b * QL + row0)) * D;
      #pragma unroll
      for (int dt = 0; dt < 8; ++dt) {
        float4 c0 = *(const float4*)&osrc[(size_t)l16 * D + dt * 16 + quad * 4];
        float4 c1 = *(const float4*)&osrc[(size_t)(16 + l16) * D + dt * 16 + quad * 4];
        float4 w0 = {(o0[dt][0] + c0.x) * i0, (o0[dt][1] + c0.y) * i0,
                     (o0[dt][2] + c0.z) * i0, (o0[dt][3] + c0.w) * i0};
        float4 w1 = {(o1[dt][0] + c1.x) * i1, (o1[dt][1] + c1.y) * i1,
                     (o1[dt][2] + c1.z) * i1, (o1[dt][3] + c1.w) * i1};
        *(float4*)&Ob[(size_t)l16 * D + dt * 16 + quad * 4]        = w0;
        *(float4*)&Ob[(size_t)(16 + l16) * D + dt * 16 + quad * 4] = w1;
      }
    }
  }
}

extern "C" void kernel_launch(void* const* d_in, const int* in_sizes, int n_in,
                              void* d_out, int out_size, void* d_ws, size_t ws_size,
                              hipStream_t stream) {
  const float* Qp = (const float*)d_in[0];
  const float* Kp = (const float*)d_in[1];
  const float* Vp = (const float*)d_in[2];
  const int*   VL = (const int*)d_in[3];
  float* Op = (float*)d_out;

  const size_t n_pairs = (size_t)BATCH * (QL / BQ);  // 256
  const size_t need = n_pairs * BQ * D * 4           // partials (ks=1)
                    + n_pairs * 256 * 4              // row sums [pair][2][128]
                    + n_pairs * 4;                   // arrival counters
  if (d_ws != nullptr && ws_size >= need) {
    float* wsO = (float*)d_ws;
    float* wsL = wsO + n_pairs * BQ * D;
    int*   wsC = (int*)(wsL + n_pairs * 256);
    hipMemsetAsync(wsC, 0, n_pairs * sizeof(int), stream);
    attn_fwd<<<dim3(2 * (int)n_pairs), dim3(256), 0, stream>>>(
        Qp, Kp, Vp, VL, Op, wsO, wsL, wsC, 2);
  } else {
    attn_fwd<<<dim3((int)n_pairs), dim3(256), 0, stream>>>(
        Qp, Kp, Vp, VL, Op, nullptr, nullptr, nullptr, 1);
  }
}